// Round 1
// baseline (2000.181 us; speedup 1.0000x reference)
//
#include <hip/hip_runtime.h>
#include <math.h>

// GAT: 3 hidden GATConv layers (H=4, D=64, HID=256) + LN + leaky + residual,
// then output GATConv (H=1, C=40). N=100000 nodes, E=1600000 edges.
//
// Strategy (round 1, correctness-first fp32 baseline):
//  - Build CSR by dst ONCE per launch (edge list is layer-invariant).
//    No prefix scan: segments allocated with a global atomic (order of
//    segments is irrelevant; max/sum are commutative).
//  - Per layer: tiled fp32 GEMM (128x128x16, 8x8/thread) -> scores (wave/node)
//    -> wave-per-dst aggregation with fused bias+ELU+LN+leaky+residual.
//  - Output layer: LDS-resident W_o wave-per-node GEMM + aggregation (C=40).

#define NEG_SLOPE 0.2f

__device__ __forceinline__ float leaky(float x) { return x >= 0.f ? x : NEG_SLOPE * x; }

// ---------------- CSR build ----------------
__global__ void zero_i32(int* __restrict__ p, int n) {
    int i = blockIdx.x * blockDim.x + threadIdx.x;
    if (i < n) p[i] = 0;
}

__global__ void hist_kernel(const int* __restrict__ dst, int* __restrict__ counts, int E) {
    int e = blockIdx.x * blockDim.x + threadIdx.x;
    if (e < E) atomicAdd(&counts[dst[e]], 1);
}

__global__ void alloc_kernel(const int* __restrict__ counts, int* __restrict__ start,
                             int* __restrict__ cursor, int* __restrict__ total, int N) {
    int n = blockIdx.x * blockDim.x + threadIdx.x;
    if (n < N) {
        int c = counts[n];
        int s = atomicAdd(total, c);
        start[n] = s;
        cursor[n] = s;
    }
}

__global__ void scatter_kernel(const int* __restrict__ src, const int* __restrict__ dst,
                               int* __restrict__ cursor, int* __restrict__ col, int E) {
    int e = blockIdx.x * blockDim.x + threadIdx.x;
    if (e < E) {
        int p = atomicAdd(&cursor[dst[e]], 1);
        col[p] = src[e];
    }
}
// After scatter: edges of node n are col[start[n] .. cursor[n]) (cursor == end).

// ---------------- fp32 tiled GEMM: C[M,256] = A[M,256] * B[256,256] ----------------
__global__ __launch_bounds__(256) void gemm_f32(const float* __restrict__ A,
                                                const float* __restrict__ B,
                                                float* __restrict__ C, int M) {
    __shared__ float As[16][132];  // [k][m], +4 pad
    __shared__ float Bs[16][132];  // [k][n]
    const int tid = threadIdx.x;
    const int bx = blockIdx.x & 1;   // 256/128 = 2 col blocks
    const int by = blockIdx.x >> 1;
    const int row0 = by * 128, col0 = bx * 128;
    const int tx = tid & 15, ty = tid >> 4;

    float acc[8][8];
#pragma unroll
    for (int i = 0; i < 8; ++i)
#pragma unroll
        for (int j = 0; j < 8; ++j) acc[i][j] = 0.f;

    for (int kb = 0; kb < 256; kb += 16) {
#pragma unroll
        for (int i = 0; i < 2; ++i) {
            int f = tid + 256 * i;  // 0..511 float4 slots
            // A tile: 128 rows x 16 cols
            int m = f >> 2, c4 = (f & 3) << 2;
            int gr = row0 + m;
            float4 v = make_float4(0.f, 0.f, 0.f, 0.f);
            if (gr < M) v = *(const float4*)(A + (size_t)gr * 256 + kb + c4);
            As[c4 + 0][m] = v.x;
            As[c4 + 1][m] = v.y;
            As[c4 + 2][m] = v.z;
            As[c4 + 3][m] = v.w;
            // B tile: 16 rows x 128 cols
            int k = f >> 5, n4 = (f & 31) << 2;
            *(float4*)&Bs[k][n4] = *(const float4*)(B + (size_t)(kb + k) * 256 + col0 + n4);
        }
        __syncthreads();
#pragma unroll
        for (int k = 0; k < 16; ++k) {
            float4 a0 = *(const float4*)&As[k][ty * 8];
            float4 a1 = *(const float4*)&As[k][ty * 8 + 4];
            float4 b0 = *(const float4*)&Bs[k][tx * 8];
            float4 b1 = *(const float4*)&Bs[k][tx * 8 + 4];
            float a[8] = {a0.x, a0.y, a0.z, a0.w, a1.x, a1.y, a1.z, a1.w};
            float b[8] = {b0.x, b0.y, b0.z, b0.w, b1.x, b1.y, b1.z, b1.w};
#pragma unroll
            for (int i = 0; i < 8; ++i)
#pragma unroll
                for (int j = 0; j < 8; ++j) acc[i][j] = fmaf(a[i], b[j], acc[i][j]);
        }
        __syncthreads();
    }
#pragma unroll
    for (int i = 0; i < 8; ++i) {
        int gr = row0 + ty * 8 + i;
        if (gr < M) {
            float4 v0 = {acc[i][0], acc[i][1], acc[i][2], acc[i][3]};
            float4 v1 = {acc[i][4], acc[i][5], acc[i][6], acc[i][7]};
            *(float4*)(C + (size_t)gr * 256 + col0 + tx * 8) = v0;
            *(float4*)(C + (size_t)gr * 256 + col0 + tx * 8 + 4) = v1;
        }
    }
}

// ---------------- per-node attention scores: el/er [N,4] ----------------
__global__ __launch_bounds__(256) void scores_kernel(const float* __restrict__ feat,
                                                     const float* __restrict__ al,
                                                     const float* __restrict__ ar,
                                                     float* __restrict__ el,
                                                     float* __restrict__ er, int N) {
    int node = blockIdx.x * 4 + (threadIdx.x >> 6);
    int lane = threadIdx.x & 63;
    if (node >= N) return;
    float4 f = *(const float4*)(feat + (size_t)node * 256 + lane * 4);
    float4 a = *(const float4*)(al + lane * 4);
    float4 r = *(const float4*)(ar + lane * 4);
    float pl = f.x * a.x + f.y * a.y + f.z * a.z + f.w * a.w;
    float pr = f.x * r.x + f.y * r.y + f.z * r.z + f.w * r.w;
    // reduce within each 16-lane head group (head = lane>>4)
#pragma unroll
    for (int off = 8; off >= 1; off >>= 1) {
        pl += __shfl_xor(pl, off);
        pr += __shfl_xor(pr, off);
    }
    if ((lane & 15) == 0) {
        int head = lane >> 4;
        el[node * 4 + head] = pl;
        er[node * 4 + head] = pr;
    }
}

// ---------------- hidden-layer aggregation + fused epilogue ----------------
__global__ __launch_bounds__(256) void aggregate_hidden(
    const float* __restrict__ feat, const float* __restrict__ el, const float* __restrict__ er,
    const int* __restrict__ start, const int* __restrict__ endp, const int* __restrict__ col,
    const float* __restrict__ bias, const float* __restrict__ lng, const float* __restrict__ lnb,
    const float* __restrict__ h_in, float* __restrict__ h_out, int N) {
    int node = blockIdx.x * 4 + (threadIdx.x >> 6);
    int lane = threadIdx.x & 63;
    if (node >= N) return;
    int begin = __builtin_amdgcn_readfirstlane(start[node]);
    int end = __builtin_amdgcn_readfirstlane(endp[node]);
    const float4 er4 = *(const float4*)(er + (size_t)node * 4);

    // Phase A1: per-head segment max
    float m0 = -INFINITY, m1 = -INFINITY, m2 = -INFINITY, m3 = -INFINITY;
    for (int e = begin + lane; e < end; e += 64) {
        int s = col[e];
        float4 e4 = *(const float4*)(el + (size_t)s * 4);
        m0 = fmaxf(m0, leaky(e4.x + er4.x));
        m1 = fmaxf(m1, leaky(e4.y + er4.y));
        m2 = fmaxf(m2, leaky(e4.z + er4.z));
        m3 = fmaxf(m3, leaky(e4.w + er4.w));
    }
#pragma unroll
    for (int off = 32; off >= 1; off >>= 1) {
        m0 = fmaxf(m0, __shfl_xor(m0, off));
        m1 = fmaxf(m1, __shfl_xor(m1, off));
        m2 = fmaxf(m2, __shfl_xor(m2, off));
        m3 = fmaxf(m3, __shfl_xor(m3, off));
    }
    // Phase A2: sum of exp
    float s0 = 0.f, s1 = 0.f, s2 = 0.f, s3 = 0.f;
    for (int e = begin + lane; e < end; e += 64) {
        int s = col[e];
        float4 e4 = *(const float4*)(el + (size_t)s * 4);
        s0 += __expf(leaky(e4.x + er4.x) - m0);
        s1 += __expf(leaky(e4.y + er4.y) - m1);
        s2 += __expf(leaky(e4.z + er4.z) - m2);
        s3 += __expf(leaky(e4.w + er4.w) - m3);
    }
#pragma unroll
    for (int off = 32; off >= 1; off >>= 1) {
        s0 += __shfl_xor(s0, off);
        s1 += __shfl_xor(s1, off);
        s2 += __shfl_xor(s2, off);
        s3 += __shfl_xor(s3, off);
    }

    int head = lane >> 4;
    float mh = (head & 2) ? ((head & 1) ? m3 : m2) : ((head & 1) ? m1 : m0);
    float sh = (head & 2) ? ((head & 1) ? s3 : s2) : ((head & 1) ? s1 : s0);
    float erh = (head & 2) ? ((head & 1) ? er4.w : er4.z) : ((head & 1) ? er4.y : er4.x);
    float inv = sh > 0.f ? 1.f / sh : 0.f;

    // Phase B: weighted gather-accumulate; lane owns channels [4*lane, 4*lane+4)
    int ch = lane * 4;
    const float* fbase = feat + ch;
    float4 acc = {0.f, 0.f, 0.f, 0.f};
    int e = begin;
    for (; e + 1 < end; e += 2) {
        int sA = col[e], sB = col[e + 1];
        float wA = __expf(leaky(el[(size_t)sA * 4 + head] + erh) - mh) * inv;
        float wB = __expf(leaky(el[(size_t)sB * 4 + head] + erh) - mh) * inv;
        float4 fA = *(const float4*)(fbase + (size_t)sA * 256);
        float4 fB = *(const float4*)(fbase + (size_t)sB * 256);
        acc.x = fmaf(wA, fA.x, acc.x); acc.y = fmaf(wA, fA.y, acc.y);
        acc.z = fmaf(wA, fA.z, acc.z); acc.w = fmaf(wA, fA.w, acc.w);
        acc.x = fmaf(wB, fB.x, acc.x); acc.y = fmaf(wB, fB.y, acc.y);
        acc.z = fmaf(wB, fB.z, acc.z); acc.w = fmaf(wB, fB.w, acc.w);
    }
    if (e < end) {
        int sA = col[e];
        float wA = __expf(leaky(el[(size_t)sA * 4 + head] + erh) - mh) * inv;
        float4 fA = *(const float4*)(fbase + (size_t)sA * 256);
        acc.x = fmaf(wA, fA.x, acc.x); acc.y = fmaf(wA, fA.y, acc.y);
        acc.z = fmaf(wA, fA.z, acc.z); acc.w = fmaf(wA, fA.w, acc.w);
    }

    // Epilogue: +bias, ELU, LayerNorm(256), leaky(0.2), +residual
    float4 bb = *(const float4*)(bias + ch);
    float x0 = acc.x + bb.x, x1 = acc.y + bb.y, x2 = acc.z + bb.z, x3 = acc.w + bb.w;
    x0 = x0 > 0.f ? x0 : expm1f(x0);
    x1 = x1 > 0.f ? x1 : expm1f(x1);
    x2 = x2 > 0.f ? x2 : expm1f(x2);
    x3 = x3 > 0.f ? x3 : expm1f(x3);
    float lsum = x0 + x1 + x2 + x3;
    float lsq = x0 * x0 + x1 * x1 + x2 * x2 + x3 * x3;
#pragma unroll
    for (int off = 32; off >= 1; off >>= 1) {
        lsum += __shfl_xor(lsum, off);
        lsq += __shfl_xor(lsq, off);
    }
    float mu = lsum * (1.f / 256.f);
    float var = lsq * (1.f / 256.f) - mu * mu;
    float rstd = rsqrtf(var + 1e-5f);
    float4 g4 = *(const float4*)(lng + ch);
    float4 b4 = *(const float4*)(lnb + ch);
    float4 hi = *(const float4*)(h_in + (size_t)node * 256 + ch);
    float y0 = (x0 - mu) * rstd * g4.x + b4.x;
    float y1 = (x1 - mu) * rstd * g4.y + b4.y;
    float y2 = (x2 - mu) * rstd * g4.z + b4.z;
    float y3 = (x3 - mu) * rstd * g4.w + b4.w;
    y0 = (y0 >= 0.f ? y0 : 0.2f * y0) + hi.x;
    y1 = (y1 >= 0.f ? y1 : 0.2f * y1) + hi.y;
    y2 = (y2 >= 0.f ? y2 : 0.2f * y2) + hi.z;
    y3 = (y3 >= 0.f ? y3 : 0.2f * y3) + hi.w;
    float4 out = {y0, y1, y2, y3};
    *(float4*)(h_out + (size_t)node * 256 + ch) = out;
}

// ---------------- output GEMM: feat_o[N,40] = h[N,256] @ W_o[256,40], + el_o/er_o ----------------
__global__ __launch_bounds__(256) void gemm_out_kernel(const float* __restrict__ h,
                                                       const float* __restrict__ W,
                                                       const float* __restrict__ alo,
                                                       const float* __restrict__ aro,
                                                       float* __restrict__ feat_o,
                                                       float* __restrict__ elo,
                                                       float* __restrict__ ero, int N) {
    __shared__ float Ws[256 * 40];
    __shared__ float hrow[4][256];
    int tid = threadIdx.x;
#pragma unroll
    for (int i = 0; i < 10; ++i) {
        int f = tid + 256 * i;  // float4 slot, 2560 total
        *(float4*)&Ws[f * 4] = *(const float4*)(W + (size_t)f * 4);
    }
    __syncthreads();
    int wid = tid >> 6, lane = tid & 63;
    int cc = lane < 40 ? lane : 0;
    float al_c = (lane < 40) ? alo[lane] : 0.f;
    float ar_c = (lane < 40) ? aro[lane] : 0.f;
    for (int it = 0; it < 4; ++it) {
        int node = blockIdx.x * 16 + wid * 4 + it;
        if (node >= N) continue;  // wave-uniform
        *(float4*)&hrow[wid][lane * 4] = *(const float4*)(h + (size_t)node * 256 + lane * 4);
        asm volatile("s_waitcnt lgkmcnt(0)" ::: "memory");
        float acc0 = 0.f, acc1 = 0.f;
#pragma unroll 8
        for (int k4 = 0; k4 < 64; ++k4) {
            float4 hv = *(const float4*)&hrow[wid][k4 * 4];
            acc0 = fmaf(hv.x, Ws[(k4 * 4 + 0) * 40 + cc], acc0);
            acc1 = fmaf(hv.y, Ws[(k4 * 4 + 1) * 40 + cc], acc1);
            acc0 = fmaf(hv.z, Ws[(k4 * 4 + 2) * 40 + cc], acc0);
            acc1 = fmaf(hv.w, Ws[(k4 * 4 + 3) * 40 + cc], acc1);
        }
        float acc = acc0 + acc1;
        if (lane < 40) feat_o[(size_t)node * 40 + lane] = acc;
        float pl = acc * al_c, pr = acc * ar_c;
#pragma unroll
        for (int off = 32; off >= 1; off >>= 1) {
            pl += __shfl_xor(pl, off);
            pr += __shfl_xor(pr, off);
        }
        if (lane == 0) {
            elo[node] = pl;
            ero[node] = pr;
        }
        asm volatile("s_waitcnt lgkmcnt(0)" ::: "memory");
    }
}

// ---------------- output aggregation: logits[N,40] ----------------
__global__ __launch_bounds__(256) void aggregate_out(const float* __restrict__ feat_o,
                                                     const float* __restrict__ elo,
                                                     const float* __restrict__ ero,
                                                     const int* __restrict__ start,
                                                     const int* __restrict__ endp,
                                                     const int* __restrict__ col,
                                                     const float* __restrict__ bias_o,
                                                     float* __restrict__ out, int N) {
    int node = blockIdx.x * 4 + (threadIdx.x >> 6);
    int lane = threadIdx.x & 63;
    if (node >= N) return;
    int begin = __builtin_amdgcn_readfirstlane(start[node]);
    int end = __builtin_amdgcn_readfirstlane(endp[node]);
    float ern = ero[node];
    float m = -INFINITY;
    for (int e = begin + lane; e < end; e += 64) m = fmaxf(m, leaky(elo[col[e]] + ern));
#pragma unroll
    for (int off = 32; off >= 1; off >>= 1) m = fmaxf(m, __shfl_xor(m, off));
    float s = 0.f;
    for (int e = begin + lane; e < end; e += 64) s += __expf(leaky(elo[col[e]] + ern) - m);
#pragma unroll
    for (int off = 32; off >= 1; off >>= 1) s += __shfl_xor(s, off);
    float inv = s > 0.f ? 1.f / s : 0.f;
    int cc = lane < 40 ? lane : 0;
    float acc = 0.f;
    int e = begin;
    for (; e + 1 < end; e += 2) {
        int sA = col[e], sB = col[e + 1];
        float wA = __expf(leaky(elo[sA] + ern) - m) * inv;
        float wB = __expf(leaky(elo[sB] + ern) - m) * inv;
        float fA = feat_o[(size_t)sA * 40 + cc];
        float fB = feat_o[(size_t)sB * 40 + cc];
        acc = fmaf(wA, fA, acc);
        acc = fmaf(wB, fB, acc);
    }
    if (e < end) {
        int sA = col[e];
        float wA = __expf(leaky(elo[sA] + ern) - m) * inv;
        acc = fmaf(wA, feat_o[(size_t)sA * 40 + cc], acc);
    }
    if (lane < 40) out[(size_t)node * 40 + lane] = acc + bias_o[lane];
}

// ---------------- launcher ----------------
extern "C" void kernel_launch(void* const* d_in, const int* in_sizes, int n_in,
                              void* d_out, int out_size, void* d_ws, size_t ws_size,
                              hipStream_t stream) {
    const float* x = (const float*)d_in[0];
    const float* W_h = (const float*)d_in[1];
    const float* al_h = (const float*)d_in[2];
    const float* ar_h = (const float*)d_in[3];
    const float* bias_h = (const float*)d_in[4];
    const float* ln_g = (const float*)d_in[5];
    const float* ln_b = (const float*)d_in[6];
    const float* W_o = (const float*)d_in[7];
    const float* al_o = (const float*)d_in[8];
    const float* ar_o = (const float*)d_in[9];
    const float* bias_o = (const float*)d_in[10];
    const int* esrc = (const int*)d_in[11];
    const int* edst = (const int*)d_in[12];
    const int N = in_sizes[0] / 256;
    const int E = in_sizes[11];
    float* out = (float*)d_out;

    char* ws = (char*)d_ws;
    size_t off = 0;
    auto walloc = [&](size_t bytes) -> void* {
        void* p = ws + off;
        off += (bytes + 255) & ~(size_t)255;
        return p;
    };
    float* h = (float*)walloc((size_t)N * 256 * 4);
    float* feat = (float*)walloc((size_t)N * 256 * 4);
    float* el = (float*)walloc((size_t)N * 4 * 4);
    float* er = (float*)walloc((size_t)N * 4 * 4);
    int* counts = (int*)walloc(((size_t)N + 1) * 4);  // counts[N] is the global cursor
    int* start = (int*)walloc((size_t)N * 4);
    int* endp = (int*)walloc((size_t)N * 4);
    int* col = (int*)walloc((size_t)E * 4);
    if (off > ws_size) return;  // workspace too small; bail (output stays poisoned)

    const int TB = 256;
    zero_i32<<<(N + 1 + TB - 1) / TB, TB, 0, stream>>>(counts, N + 1);
    hist_kernel<<<(E + TB - 1) / TB, TB, 0, stream>>>(edst, counts, E);
    alloc_kernel<<<(N + TB - 1) / TB, TB, 0, stream>>>(counts, start, endp, counts + N, N);
    scatter_kernel<<<(E + TB - 1) / TB, TB, 0, stream>>>(esrc, edst, endp, col, E);

    const int nb4 = (N + 3) / 4;
    for (int l = 0; l < 3; ++l) {
        const float* hin = (l == 0) ? x : h;
        dim3 ggrid(((N + 127) / 128) * 2);
        gemm_f32<<<ggrid, 256, 0, stream>>>(hin, W_h + (size_t)l * 256 * 256, feat, N);
        scores_kernel<<<nb4, 256, 0, stream>>>(feat, al_h + l * 256, ar_h + l * 256, el, er, N);
        aggregate_hidden<<<nb4, 256, 0, stream>>>(feat, el, er, start, endp, col,
                                                  bias_h + l * 256, ln_g + l * 256,
                                                  ln_b + l * 256, hin, h, N);
    }
    // output layer (reuse feat/el/er buffers)
    float* feat_o = feat;
    float* elo = el;
    float* ero = er;
    gemm_out_kernel<<<(N + 15) / 16, 256, 0, stream>>>(h, W_o, al_o, ar_o, feat_o, elo, ero, N);
    aggregate_out<<<nb4, 256, 0, stream>>>(feat_o, elo, ero, start, endp, col, bias_o, out, N);
}

// Round 2
// 1311.227 us; speedup vs baseline: 1.5254x; 1.5254x over previous
//
#include <hip/hip_runtime.h>
#include <math.h>

// GAT: 3 hidden GATConv layers (H=4, D=64, HID=256) + LN + leaky + residual,
// then output GATConv (H=1, C=40). N=100000 nodes, E=1600000 edges.
//
// Round 2: bf16 MFMA GEMM (16x16x32, 128x128 tile) writing bf16 feat;
// aggregation gathers bf16 feat (512B/edge, L3-resident). fp32 accumulate
// everywhere; residual stream h stays fp32.

#define NEG_SLOPE 0.2f

typedef __attribute__((ext_vector_type(8))) short bf16x8;
typedef __attribute__((ext_vector_type(4))) float floatx4;

__device__ __forceinline__ float leaky(float x) { return x >= 0.f ? x : NEG_SLOPE * x; }

__device__ __forceinline__ unsigned short f2bf(float f) {
    unsigned u = __builtin_bit_cast(unsigned, f);
    u += 0x7fffu + ((u >> 16) & 1u);  // RNE (inputs are finite/sane)
    return (unsigned short)(u >> 16);
}
__device__ __forceinline__ float bf2f(unsigned short h) {
    unsigned u = ((unsigned)h) << 16;
    return __builtin_bit_cast(float, u);
}

// ---------------- CSR build ----------------
__global__ void zero_i32(int* __restrict__ p, int n) {
    int i = blockIdx.x * blockDim.x + threadIdx.x;
    if (i < n) p[i] = 0;
}

__global__ void hist_kernel(const int* __restrict__ dst, int* __restrict__ counts, int E) {
    int e = blockIdx.x * blockDim.x + threadIdx.x;
    if (e < E) atomicAdd(&counts[dst[e]], 1);
}

__global__ void alloc_kernel(const int* __restrict__ counts, int* __restrict__ start,
                             int* __restrict__ cursor, int* __restrict__ total, int N) {
    int n = blockIdx.x * blockDim.x + threadIdx.x;
    if (n < N) {
        int c = counts[n];
        int s = atomicAdd(total, c);
        start[n] = s;
        cursor[n] = s;
    }
}

__global__ void scatter_kernel(const int* __restrict__ src, const int* __restrict__ dst,
                               int* __restrict__ cursor, int* __restrict__ col, int E) {
    int e = blockIdx.x * blockDim.x + threadIdx.x;
    if (e < E) {
        int p = atomicAdd(&cursor[dst[e]], 1);
        col[p] = src[e];
    }
}

// ---------------- weight pre-transpose: Wt[l][n][k] = bf16(W[l][k][n]) ----------------
__global__ void transpose_w(const float* __restrict__ W, unsigned short* __restrict__ Wt) {
    int idx = blockIdx.x * 256 + threadIdx.x;  // 3*65536 total
    int l = idx >> 16, r = idx & 65535;
    int k = r >> 8, n = r & 255;
    Wt[l * 65536 + n * 256 + k] = f2bf(W[l * 65536 + k * 256 + n]);
}

// ---------------- bf16 MFMA GEMM: Cb[M,256] = bf16( A[M,256] @ W ) ----------------
// A fp32 (converted to bf16 during LDS staging), Wt bf16 [n][k] pre-transposed.
#define LDSK 40  // row stride in bf16 elems: 80B -> ds_read_b128 16B-aligned, 2-way banks (free)
__global__ __launch_bounds__(256, 2) void gemm_bf16(const float* __restrict__ A,
                                                    const unsigned short* __restrict__ Wt,
                                                    unsigned short* __restrict__ Cb, int M) {
    __shared__ unsigned short As[128 * LDSK];
    __shared__ unsigned short Bs[128 * LDSK];
    const int tid = threadIdx.x;
    const int bx = blockIdx.x & 1;   // 2 col-blocks of 128
    const int by = blockIdx.x >> 1;
    const int row0 = by * 128, col0 = bx * 128;
    const int lane = tid & 63, wid = tid >> 6;
    const int wm = (wid & 1) * 64, wn = (wid >> 1) * 64;  // wave tile 64x64

    floatx4 acc[4][4] = {};

    for (int kb = 0; kb < 256; kb += 32) {
#pragma unroll
        for (int i = 0; i < 4; ++i) {
            int idx = tid + 256 * i;       // 1024 slots of 4 elems
            int r = idx >> 3, k4 = idx & 7;
            int gr = row0 + r;
            float4 v = make_float4(0.f, 0.f, 0.f, 0.f);
            if (gr < M) v = *(const float4*)(A + (size_t)gr * 256 + kb + k4 * 4);
            ushort4 s;
            s.x = f2bf(v.x); s.y = f2bf(v.y); s.z = f2bf(v.z); s.w = f2bf(v.w);
            *(ushort4*)&As[r * LDSK + k4 * 4] = s;
            int n = col0 + r;
            ushort4 b = *(const ushort4*)(Wt + (size_t)n * 256 + kb + k4 * 4);
            *(ushort4*)&Bs[r * LDSK + k4 * 4] = b;
        }
        __syncthreads();
        const int q = lane >> 4, m = lane & 15;
        bf16x8 af[4], bfr[4];
#pragma unroll
        for (int i = 0; i < 4; ++i) {
            af[i] = *(const bf16x8*)&As[(wm + i * 16 + m) * LDSK + q * 8];
            bfr[i] = *(const bf16x8*)&Bs[(wn + i * 16 + m) * LDSK + q * 8];
        }
#pragma unroll
        for (int i = 0; i < 4; ++i)
#pragma unroll
            for (int j = 0; j < 4; ++j)
                acc[i][j] = __builtin_amdgcn_mfma_f32_16x16x32_bf16(af[i], bfr[j], acc[i][j], 0, 0, 0);
        __syncthreads();
    }

    // epilogue: C/D layout col=lane&15, row=(lane>>4)*4+reg  [verified m89]
    const int q = lane >> 4, c = lane & 15;
#pragma unroll
    for (int i = 0; i < 4; ++i)
#pragma unroll
        for (int j = 0; j < 4; ++j)
#pragma unroll
            for (int r = 0; r < 4; ++r) {
                int grow = row0 + wm + i * 16 + q * 4 + r;
                int gcol = col0 + wn + j * 16 + c;
                if (grow < M) Cb[(size_t)grow * 256 + gcol] = f2bf(acc[i][j][r]);
            }
}

// ---------------- per-node attention scores from bf16 feat ----------------
__global__ __launch_bounds__(256) void scores_bf(const unsigned short* __restrict__ feat,
                                                 const float* __restrict__ al,
                                                 const float* __restrict__ ar,
                                                 float* __restrict__ el,
                                                 float* __restrict__ er, int N) {
    int node = blockIdx.x * 4 + (threadIdx.x >> 6);
    int lane = threadIdx.x & 63;
    if (node >= N) return;
    ushort4 u = *(const ushort4*)(feat + (size_t)node * 256 + lane * 4);
    float4 a = *(const float4*)(al + lane * 4);
    float4 r = *(const float4*)(ar + lane * 4);
    float f0 = bf2f(u.x), f1 = bf2f(u.y), f2 = bf2f(u.z), f3 = bf2f(u.w);
    float pl = f0 * a.x + f1 * a.y + f2 * a.z + f3 * a.w;
    float pr = f0 * r.x + f1 * r.y + f2 * r.z + f3 * r.w;
#pragma unroll
    for (int off = 8; off >= 1; off >>= 1) {
        pl += __shfl_xor(pl, off);
        pr += __shfl_xor(pr, off);
    }
    if ((lane & 15) == 0) {
        int head = lane >> 4;
        el[node * 4 + head] = pl;
        er[node * 4 + head] = pr;
    }
}

// ---------------- hidden-layer aggregation + fused epilogue (bf16 gather) ----------------
__global__ __launch_bounds__(256) void aggregate_hidden(
    const unsigned short* __restrict__ feat, const float* __restrict__ el,
    const float* __restrict__ er, const int* __restrict__ start, const int* __restrict__ endp,
    const int* __restrict__ col, const float* __restrict__ bias, const float* __restrict__ lng,
    const float* __restrict__ lnb, const float* __restrict__ h_in, float* __restrict__ h_out,
    int N) {
    int node = blockIdx.x * 4 + (threadIdx.x >> 6);
    int lane = threadIdx.x & 63;
    if (node >= N) return;
    int begin = __builtin_amdgcn_readfirstlane(start[node]);
    int end = __builtin_amdgcn_readfirstlane(endp[node]);
    const float4 er4 = *(const float4*)(er + (size_t)node * 4);

    // Phase A1: per-head segment max
    float m0 = -INFINITY, m1 = -INFINITY, m2 = -INFINITY, m3 = -INFINITY;
    for (int e = begin + lane; e < end; e += 64) {
        int s = col[e];
        float4 e4 = *(const float4*)(el + (size_t)s * 4);
        m0 = fmaxf(m0, leaky(e4.x + er4.x));
        m1 = fmaxf(m1, leaky(e4.y + er4.y));
        m2 = fmaxf(m2, leaky(e4.z + er4.z));
        m3 = fmaxf(m3, leaky(e4.w + er4.w));
    }
#pragma unroll
    for (int off = 32; off >= 1; off >>= 1) {
        m0 = fmaxf(m0, __shfl_xor(m0, off));
        m1 = fmaxf(m1, __shfl_xor(m1, off));
        m2 = fmaxf(m2, __shfl_xor(m2, off));
        m3 = fmaxf(m3, __shfl_xor(m3, off));
    }
    // Phase A2: sum of exp
    float s0 = 0.f, s1 = 0.f, s2 = 0.f, s3 = 0.f;
    for (int e = begin + lane; e < end; e += 64) {
        int s = col[e];
        float4 e4 = *(const float4*)(el + (size_t)s * 4);
        s0 += __expf(leaky(e4.x + er4.x) - m0);
        s1 += __expf(leaky(e4.y + er4.y) - m1);
        s2 += __expf(leaky(e4.z + er4.z) - m2);
        s3 += __expf(leaky(e4.w + er4.w) - m3);
    }
#pragma unroll
    for (int off = 32; off >= 1; off >>= 1) {
        s0 += __shfl_xor(s0, off);
        s1 += __shfl_xor(s1, off);
        s2 += __shfl_xor(s2, off);
        s3 += __shfl_xor(s3, off);
    }

    int head = lane >> 4;
    float mh = (head & 2) ? ((head & 1) ? m3 : m2) : ((head & 1) ? m1 : m0);
    float sh = (head & 2) ? ((head & 1) ? s3 : s2) : ((head & 1) ? s1 : s0);
    float erh = (head & 2) ? ((head & 1) ? er4.w : er4.z) : ((head & 1) ? er4.y : er4.x);
    float inv = sh > 0.f ? 1.f / sh : 0.f;

    // Phase B: weighted bf16 gather; lane owns channels [4*lane, 4*lane+4)
    int ch = lane * 4;
    const unsigned short* fbase = feat + ch;
    float4 acc = {0.f, 0.f, 0.f, 0.f};
    int e = begin;
    for (; e + 1 < end; e += 2) {
        int sA = col[e], sB = col[e + 1];
        float wA = __expf(leaky(el[(size_t)sA * 4 + head] + erh) - mh) * inv;
        float wB = __expf(leaky(el[(size_t)sB * 4 + head] + erh) - mh) * inv;
        ushort4 uA = *(const ushort4*)(fbase + (size_t)sA * 256);
        ushort4 uB = *(const ushort4*)(fbase + (size_t)sB * 256);
        acc.x = fmaf(wA, bf2f(uA.x), acc.x); acc.y = fmaf(wA, bf2f(uA.y), acc.y);
        acc.z = fmaf(wA, bf2f(uA.z), acc.z); acc.w = fmaf(wA, bf2f(uA.w), acc.w);
        acc.x = fmaf(wB, bf2f(uB.x), acc.x); acc.y = fmaf(wB, bf2f(uB.y), acc.y);
        acc.z = fmaf(wB, bf2f(uB.z), acc.z); acc.w = fmaf(wB, bf2f(uB.w), acc.w);
    }
    if (e < end) {
        int sA = col[e];
        float wA = __expf(leaky(el[(size_t)sA * 4 + head] + erh) - mh) * inv;
        ushort4 uA = *(const ushort4*)(fbase + (size_t)sA * 256);
        acc.x = fmaf(wA, bf2f(uA.x), acc.x); acc.y = fmaf(wA, bf2f(uA.y), acc.y);
        acc.z = fmaf(wA, bf2f(uA.z), acc.z); acc.w = fmaf(wA, bf2f(uA.w), acc.w);
    }

    // Epilogue: +bias, ELU, LayerNorm(256), leaky(0.2), +residual
    float4 bb = *(const float4*)(bias + ch);
    float x0 = acc.x + bb.x, x1 = acc.y + bb.y, x2 = acc.z + bb.z, x3 = acc.w + bb.w;
    x0 = x0 > 0.f ? x0 : expm1f(x0);
    x1 = x1 > 0.f ? x1 : expm1f(x1);
    x2 = x2 > 0.f ? x2 : expm1f(x2);
    x3 = x3 > 0.f ? x3 : expm1f(x3);
    float lsum = x0 + x1 + x2 + x3;
    float lsq = x0 * x0 + x1 * x1 + x2 * x2 + x3 * x3;
#pragma unroll
    for (int off = 32; off >= 1; off >>= 1) {
        lsum += __shfl_xor(lsum, off);
        lsq += __shfl_xor(lsq, off);
    }
    float mu = lsum * (1.f / 256.f);
    float var = lsq * (1.f / 256.f) - mu * mu;
    float rstd = rsqrtf(var + 1e-5f);
    float4 g4 = *(const float4*)(lng + ch);
    float4 b4 = *(const float4*)(lnb + ch);
    float4 hi = *(const float4*)(h_in + (size_t)node * 256 + ch);
    float y0 = (x0 - mu) * rstd * g4.x + b4.x;
    float y1 = (x1 - mu) * rstd * g4.y + b4.y;
    float y2 = (x2 - mu) * rstd * g4.z + b4.z;
    float y3 = (x3 - mu) * rstd * g4.w + b4.w;
    y0 = (y0 >= 0.f ? y0 : 0.2f * y0) + hi.x;
    y1 = (y1 >= 0.f ? y1 : 0.2f * y1) + hi.y;
    y2 = (y2 >= 0.f ? y2 : 0.2f * y2) + hi.z;
    y3 = (y3 >= 0.f ? y3 : 0.2f * y3) + hi.w;
    float4 out = {y0, y1, y2, y3};
    *(float4*)(h_out + (size_t)node * 256 + ch) = out;
}
// first-layer variant residual source: launcher passes h_in=x for l==0 (shapes match, HID==IN).

// ---------------- output GEMM: feat_o[N,40](bf16), el_o/er_o ----------------
__global__ __launch_bounds__(256) void gemm_out_kernel(const float* __restrict__ h,
                                                       const float* __restrict__ W,
                                                       const float* __restrict__ alo,
                                                       const float* __restrict__ aro,
                                                       unsigned short* __restrict__ feat_o,
                                                       float* __restrict__ elo,
                                                       float* __restrict__ ero, int N) {
    __shared__ float Ws[256 * 40];
    __shared__ float hrow[4][256];
    int tid = threadIdx.x;
#pragma unroll
    for (int i = 0; i < 10; ++i) {
        int f = tid + 256 * i;
        *(float4*)&Ws[f * 4] = *(const float4*)(W + (size_t)f * 4);
    }
    __syncthreads();
    int wid = tid >> 6, lane = tid & 63;
    int cc = lane < 40 ? lane : 0;
    float al_c = (lane < 40) ? alo[lane] : 0.f;
    float ar_c = (lane < 40) ? aro[lane] : 0.f;
    for (int it = 0; it < 4; ++it) {
        int node = blockIdx.x * 16 + wid * 4 + it;
        if (node >= N) continue;  // wave-uniform
        *(float4*)&hrow[wid][lane * 4] = *(const float4*)(h + (size_t)node * 256 + lane * 4);
        asm volatile("s_waitcnt lgkmcnt(0)" ::: "memory");
        float acc0 = 0.f, acc1 = 0.f;
#pragma unroll 8
        for (int k4 = 0; k4 < 64; ++k4) {
            float4 hv = *(const float4*)&hrow[wid][k4 * 4];
            acc0 = fmaf(hv.x, Ws[(k4 * 4 + 0) * 40 + cc], acc0);
            acc1 = fmaf(hv.y, Ws[(k4 * 4 + 1) * 40 + cc], acc1);
            acc0 = fmaf(hv.z, Ws[(k4 * 4 + 2) * 40 + cc], acc0);
            acc1 = fmaf(hv.w, Ws[(k4 * 4 + 3) * 40 + cc], acc1);
        }
        float acc = acc0 + acc1;
        if (lane < 40) feat_o[(size_t)node * 40 + lane] = f2bf(acc);
        float pl = acc * al_c, pr = acc * ar_c;
#pragma unroll
        for (int off = 32; off >= 1; off >>= 1) {
            pl += __shfl_xor(pl, off);
            pr += __shfl_xor(pr, off);
        }
        if (lane == 0) {
            elo[node] = pl;
            ero[node] = pr;
        }
        asm volatile("s_waitcnt lgkmcnt(0)" ::: "memory");
    }
}

// ---------------- output aggregation: logits[N,40] ----------------
__global__ __launch_bounds__(256) void aggregate_out(const unsigned short* __restrict__ feat_o,
                                                     const float* __restrict__ elo,
                                                     const float* __restrict__ ero,
                                                     const int* __restrict__ start,
                                                     const int* __restrict__ endp,
                                                     const int* __restrict__ col,
                                                     const float* __restrict__ bias_o,
                                                     float* __restrict__ out, int N) {
    int node = blockIdx.x * 4 + (threadIdx.x >> 6);
    int lane = threadIdx.x & 63;
    if (node >= N) return;
    int begin = __builtin_amdgcn_readfirstlane(start[node]);
    int end = __builtin_amdgcn_readfirstlane(endp[node]);
    float ern = ero[node];
    float m = -INFINITY;
    for (int e = begin + lane; e < end; e += 64) m = fmaxf(m, leaky(elo[col[e]] + ern));
#pragma unroll
    for (int off = 32; off >= 1; off >>= 1) m = fmaxf(m, __shfl_xor(m, off));
    float s = 0.f;
    for (int e = begin + lane; e < end; e += 64) s += __expf(leaky(elo[col[e]] + ern) - m);
#pragma unroll
    for (int off = 32; off >= 1; off >>= 1) s += __shfl_xor(s, off);
    float inv = s > 0.f ? 1.f / s : 0.f;
    int cc = lane < 40 ? lane : 0;
    float acc = 0.f;
    int e = begin;
    for (; e + 1 < end; e += 2) {
        int sA = col[e], sB = col[e + 1];
        float wA = __expf(leaky(elo[sA] + ern) - m) * inv;
        float wB = __expf(leaky(elo[sB] + ern) - m) * inv;
        float fA = bf2f(feat_o[(size_t)sA * 40 + cc]);
        float fB = bf2f(feat_o[(size_t)sB * 40 + cc]);
        acc = fmaf(wA, fA, acc);
        acc = fmaf(wB, fB, acc);
    }
    if (e < end) {
        int sA = col[e];
        float wA = __expf(leaky(elo[sA] + ern) - m) * inv;
        acc = fmaf(wA, bf2f(feat_o[(size_t)sA * 40 + cc]), acc);
    }
    if (lane < 40) out[(size_t)node * 40 + lane] = acc + bias_o[lane];
}

// ---------------- launcher ----------------
extern "C" void kernel_launch(void* const* d_in, const int* in_sizes, int n_in,
                              void* d_out, int out_size, void* d_ws, size_t ws_size,
                              hipStream_t stream) {
    const float* x = (const float*)d_in[0];
    const float* W_h = (const float*)d_in[1];
    const float* al_h = (const float*)d_in[2];
    const float* ar_h = (const float*)d_in[3];
    const float* bias_h = (const float*)d_in[4];
    const float* ln_g = (const float*)d_in[5];
    const float* ln_b = (const float*)d_in[6];
    const float* W_o = (const float*)d_in[7];
    const float* al_o = (const float*)d_in[8];
    const float* ar_o = (const float*)d_in[9];
    const float* bias_o = (const float*)d_in[10];
    const int* esrc = (const int*)d_in[11];
    const int* edst = (const int*)d_in[12];
    const int N = in_sizes[0] / 256;
    const int E = in_sizes[11];
    float* out = (float*)d_out;

    char* ws = (char*)d_ws;
    size_t off = 0;
    auto walloc = [&](size_t bytes) -> void* {
        void* p = ws + off;
        off += (bytes + 255) & ~(size_t)255;
        return p;
    };
    float* h = (float*)walloc((size_t)N * 256 * 4);
    unsigned short* feat_bf = (unsigned short*)walloc((size_t)N * 256 * 2);
    unsigned short* Wt = (unsigned short*)walloc((size_t)3 * 65536 * 2);
    float* el = (float*)walloc((size_t)N * 4 * 4);
    float* er = (float*)walloc((size_t)N * 4 * 4);
    int* counts = (int*)walloc(((size_t)N + 1) * 4);  // counts[N] = global cursor
    int* start = (int*)walloc((size_t)N * 4);
    int* endp = (int*)walloc((size_t)N * 4);
    int* col = (int*)walloc((size_t)E * 4);
    if (off > ws_size) return;

    const int TB = 256;
    transpose_w<<<3 * 65536 / TB, TB, 0, stream>>>(W_h, Wt);
    zero_i32<<<(N + 1 + TB - 1) / TB, TB, 0, stream>>>(counts, N + 1);
    hist_kernel<<<(E + TB - 1) / TB, TB, 0, stream>>>(edst, counts, E);
    alloc_kernel<<<(N + TB - 1) / TB, TB, 0, stream>>>(counts, start, endp, counts + N, N);
    scatter_kernel<<<(E + TB - 1) / TB, TB, 0, stream>>>(esrc, edst, endp, col, E);

    const int nb4 = (N + 3) / 4;
    const int gemm_grid = ((N + 127) / 128) * 2;
    for (int l = 0; l < 3; ++l) {
        const float* hin = (l == 0) ? x : h;
        gemm_bf16<<<gemm_grid, 256, 0, stream>>>(hin, Wt + (size_t)l * 65536, feat_bf, N);
        scores_bf<<<nb4, 256, 0, stream>>>(feat_bf, al_h + l * 256, ar_h + l * 256, el, er, N);
        aggregate_hidden<<<nb4, 256, 0, stream>>>(feat_bf, el, er, start, endp, col,
                                                  bias_h + l * 256, ln_g + l * 256,
                                                  ln_b + l * 256, hin, h, N);
    }
    // output layer (reuse feat_bf buffer for bf16 feat_o)
    unsigned short* feat_o = feat_bf;
    float* elo = el;
    float* ero = er;
    gemm_out_kernel<<<(N + 15) / 16, 256, 0, stream>>>(h, W_o, al_o, ar_o, feat_o, elo, ero, N);
    aggregate_out<<<nb4, 256, 0, stream>>>(feat_o, elo, ero, start, endp, col, bias_o, out, N);
}

// Round 3
// 1129.424 us; speedup vs baseline: 1.7710x; 1.1610x over previous
//
#include <hip/hip_runtime.h>
#include <math.h>

// GAT: 3 hidden GATConv layers (H=4, D=64, HID=256) + LN + leaky + residual,
// then output GATConv (H=1, C=40). N=100000 nodes, E=1600000 edges.
//
// Round 3: output-layer GEMM moved to MFMA (48-col padded, B fully LDS-resident),
// el_o/er_o computed by a small scores_out kernel. Hidden path unchanged from R2.

#define NEG_SLOPE 0.2f

typedef __attribute__((ext_vector_type(8))) short bf16x8;
typedef __attribute__((ext_vector_type(4))) float floatx4;

__device__ __forceinline__ float leaky(float x) { return x >= 0.f ? x : NEG_SLOPE * x; }

__device__ __forceinline__ unsigned short f2bf(float f) {
    unsigned u = __builtin_bit_cast(unsigned, f);
    u += 0x7fffu + ((u >> 16) & 1u);  // RNE
    return (unsigned short)(u >> 16);
}
__device__ __forceinline__ float bf2f(unsigned short h) {
    unsigned u = ((unsigned)h) << 16;
    return __builtin_bit_cast(float, u);
}

// ---------------- CSR build ----------------
__global__ void zero_i32(int* __restrict__ p, int n) {
    int i = blockIdx.x * blockDim.x + threadIdx.x;
    if (i < n) p[i] = 0;
}

__global__ void hist_kernel(const int* __restrict__ dst, int* __restrict__ counts, int E) {
    int e = blockIdx.x * blockDim.x + threadIdx.x;
    if (e < E) atomicAdd(&counts[dst[e]], 1);
}

__global__ void alloc_kernel(const int* __restrict__ counts, int* __restrict__ start,
                             int* __restrict__ cursor, int* __restrict__ total, int N) {
    int n = blockIdx.x * blockDim.x + threadIdx.x;
    if (n < N) {
        int c = counts[n];
        int s = atomicAdd(total, c);
        start[n] = s;
        cursor[n] = s;
    }
}

__global__ void scatter_kernel(const int* __restrict__ src, const int* __restrict__ dst,
                               int* __restrict__ cursor, int* __restrict__ col, int E) {
    int e = blockIdx.x * blockDim.x + threadIdx.x;
    if (e < E) {
        int p = atomicAdd(&cursor[dst[e]], 1);
        col[p] = src[e];
    }
}

// ---------------- weight pre-transpose: Wt[l][n][k] = bf16(W[l][k][n]) ----------------
__global__ void transpose_w(const float* __restrict__ W, unsigned short* __restrict__ Wt) {
    int idx = blockIdx.x * 256 + threadIdx.x;  // 3*65536 total
    int l = idx >> 16, r = idx & 65535;
    int k = r >> 8, n = r & 255;
    Wt[l * 65536 + n * 256 + k] = f2bf(W[l * 65536 + k * 256 + n]);
}

// W_o[256,40] -> Wt_o[48][256] bf16, zero-padded cols 40..47
__global__ void transpose_wo(const float* __restrict__ W, unsigned short* __restrict__ Wt) {
    int idx = blockIdx.x * 256 + threadIdx.x;  // 48*256 total
    int n = idx >> 8, k = idx & 255;
    Wt[n * 256 + k] = (n < 40) ? f2bf(W[k * 40 + n]) : (unsigned short)0;
}

// ---------------- bf16 MFMA GEMM: Cb[M,256] = bf16( A[M,256] @ W ) ----------------
#define LDSK 40  // row stride in bf16 elems: 16B-aligned ds_read_b128, 2-way banks (free)
__global__ __launch_bounds__(256, 2) void gemm_bf16(const float* __restrict__ A,
                                                    const unsigned short* __restrict__ Wt,
                                                    unsigned short* __restrict__ Cb, int M) {
    __shared__ unsigned short As[128 * LDSK];
    __shared__ unsigned short Bs[128 * LDSK];
    const int tid = threadIdx.x;
    const int bx = blockIdx.x & 1;
    const int by = blockIdx.x >> 1;
    const int row0 = by * 128, col0 = bx * 128;
    const int lane = tid & 63, wid = tid >> 6;
    const int wm = (wid & 1) * 64, wn = (wid >> 1) * 64;

    floatx4 acc[4][4] = {};

    for (int kb = 0; kb < 256; kb += 32) {
#pragma unroll
        for (int i = 0; i < 4; ++i) {
            int idx = tid + 256 * i;
            int r = idx >> 3, k4 = idx & 7;
            int gr = row0 + r;
            float4 v = make_float4(0.f, 0.f, 0.f, 0.f);
            if (gr < M) v = *(const float4*)(A + (size_t)gr * 256 + kb + k4 * 4);
            ushort4 s;
            s.x = f2bf(v.x); s.y = f2bf(v.y); s.z = f2bf(v.z); s.w = f2bf(v.w);
            *(ushort4*)&As[r * LDSK + k4 * 4] = s;
            int n = col0 + r;
            ushort4 b = *(const ushort4*)(Wt + (size_t)n * 256 + kb + k4 * 4);
            *(ushort4*)&Bs[r * LDSK + k4 * 4] = b;
        }
        __syncthreads();
        const int q = lane >> 4, m = lane & 15;
        bf16x8 af[4], bfr[4];
#pragma unroll
        for (int i = 0; i < 4; ++i) {
            af[i] = *(const bf16x8*)&As[(wm + i * 16 + m) * LDSK + q * 8];
            bfr[i] = *(const bf16x8*)&Bs[(wn + i * 16 + m) * LDSK + q * 8];
        }
#pragma unroll
        for (int i = 0; i < 4; ++i)
#pragma unroll
            for (int j = 0; j < 4; ++j)
                acc[i][j] = __builtin_amdgcn_mfma_f32_16x16x32_bf16(af[i], bfr[j], acc[i][j], 0, 0, 0);
        __syncthreads();
    }

    const int q = lane >> 4, c = lane & 15;
#pragma unroll
    for (int i = 0; i < 4; ++i)
#pragma unroll
        for (int j = 0; j < 4; ++j)
#pragma unroll
            for (int r = 0; r < 4; ++r) {
                int grow = row0 + wm + i * 16 + q * 4 + r;
                int gcol = col0 + wn + j * 16 + c;
                if (grow < M) Cb[(size_t)grow * 256 + gcol] = f2bf(acc[i][j][r]);
            }
}

// ---------------- output MFMA GEMM: feat_o[N,40] bf16 = h[N,256] @ W_o ----------------
#define BSTRIDE 264  // 48 rows x 264 ushorts (132 dwords; 16-lane b128 -> 2-way banks, free)
__global__ __launch_bounds__(256) void gemm_out_mfma(const float* __restrict__ h,
                                                     const unsigned short* __restrict__ Wt,
                                                     unsigned short* __restrict__ feat_o, int N) {
    __shared__ unsigned short As[128 * LDSK];
    __shared__ unsigned short Bs[48 * BSTRIDE];
    const int tid = threadIdx.x;
    const int row0 = blockIdx.x * 128;
    const int lane = tid & 63, wid = tid >> 6;

    // load all of B once: 48x256 bf16, 1536 16B chunks
#pragma unroll
    for (int i = 0; i < 6; ++i) {
        int f = tid + 256 * i;
        int n = f >> 5, kk = (f & 31) * 8;
        *(bf16x8*)&Bs[n * BSTRIDE + kk] = *(const bf16x8*)(Wt + n * 256 + kk);
    }
    __syncthreads();

    floatx4 acc[2][3] = {};
    for (int kb = 0; kb < 256; kb += 32) {
#pragma unroll
        for (int i = 0; i < 4; ++i) {
            int idx = tid + 256 * i;
            int r = idx >> 3, k4 = idx & 7;
            int gr = row0 + r;
            float4 v = make_float4(0.f, 0.f, 0.f, 0.f);
            if (gr < N) v = *(const float4*)(h + (size_t)gr * 256 + kb + k4 * 4);
            ushort4 s;
            s.x = f2bf(v.x); s.y = f2bf(v.y); s.z = f2bf(v.z); s.w = f2bf(v.w);
            *(ushort4*)&As[r * LDSK + k4 * 4] = s;
        }
        __syncthreads();
        const int q = lane >> 4, m = lane & 15;
        bf16x8 af[2], bfr[3];
#pragma unroll
        for (int i = 0; i < 2; ++i)
            af[i] = *(const bf16x8*)&As[(wid * 32 + i * 16 + m) * LDSK + q * 8];
#pragma unroll
        for (int j = 0; j < 3; ++j)
            bfr[j] = *(const bf16x8*)&Bs[(j * 16 + m) * BSTRIDE + kb + q * 8];
#pragma unroll
        for (int i = 0; i < 2; ++i)
#pragma unroll
            for (int j = 0; j < 3; ++j)
                acc[i][j] = __builtin_amdgcn_mfma_f32_16x16x32_bf16(af[i], bfr[j], acc[i][j], 0, 0, 0);
        __syncthreads();
    }

    const int q = lane >> 4, c = lane & 15;
#pragma unroll
    for (int i = 0; i < 2; ++i)
#pragma unroll
        for (int j = 0; j < 3; ++j)
#pragma unroll
            for (int r = 0; r < 4; ++r) {
                int grow = row0 + wid * 32 + i * 16 + q * 4 + r;
                int gcol = j * 16 + c;
                if (grow < N && gcol < 40) feat_o[(size_t)grow * 40 + gcol] = f2bf(acc[i][j][r]);
            }
}

// ---------------- output scores: el_o/er_o[N] from bf16 feat_o ----------------
__global__ __launch_bounds__(256) void scores_out(const unsigned short* __restrict__ feat_o,
                                                  const float* __restrict__ alo,
                                                  const float* __restrict__ aro,
                                                  float* __restrict__ elo,
                                                  float* __restrict__ ero, int N) {
    int node = blockIdx.x * 4 + (threadIdx.x >> 6);
    int lane = threadIdx.x & 63;
    if (node >= N) return;
    float v = 0.f, a = 0.f, r = 0.f;
    if (lane < 40) {
        v = bf2f(feat_o[(size_t)node * 40 + lane]);
        a = alo[lane];
        r = aro[lane];
    }
    float pl = v * a, pr = v * r;
#pragma unroll
    for (int off = 32; off >= 1; off >>= 1) {
        pl += __shfl_xor(pl, off);
        pr += __shfl_xor(pr, off);
    }
    if (lane == 0) {
        elo[node] = pl;
        ero[node] = pr;
    }
}

// ---------------- per-node attention scores from bf16 feat ----------------
__global__ __launch_bounds__(256) void scores_bf(const unsigned short* __restrict__ feat,
                                                 const float* __restrict__ al,
                                                 const float* __restrict__ ar,
                                                 float* __restrict__ el,
                                                 float* __restrict__ er, int N) {
    int node = blockIdx.x * 4 + (threadIdx.x >> 6);
    int lane = threadIdx.x & 63;
    if (node >= N) return;
    ushort4 u = *(const ushort4*)(feat + (size_t)node * 256 + lane * 4);
    float4 a = *(const float4*)(al + lane * 4);
    float4 r = *(const float4*)(ar + lane * 4);
    float f0 = bf2f(u.x), f1 = bf2f(u.y), f2 = bf2f(u.z), f3 = bf2f(u.w);
    float pl = f0 * a.x + f1 * a.y + f2 * a.z + f3 * a.w;
    float pr = f0 * r.x + f1 * r.y + f2 * r.z + f3 * r.w;
#pragma unroll
    for (int off = 8; off >= 1; off >>= 1) {
        pl += __shfl_xor(pl, off);
        pr += __shfl_xor(pr, off);
    }
    if ((lane & 15) == 0) {
        int head = lane >> 4;
        el[node * 4 + head] = pl;
        er[node * 4 + head] = pr;
    }
}

// ---------------- hidden-layer aggregation + fused epilogue (bf16 gather) ----------------
__global__ __launch_bounds__(256) void aggregate_hidden(
    const unsigned short* __restrict__ feat, const float* __restrict__ el,
    const float* __restrict__ er, const int* __restrict__ start, const int* __restrict__ endp,
    const int* __restrict__ col, const float* __restrict__ bias, const float* __restrict__ lng,
    const float* __restrict__ lnb, const float* __restrict__ h_in, float* __restrict__ h_out,
    int N) {
    int node = blockIdx.x * 4 + (threadIdx.x >> 6);
    int lane = threadIdx.x & 63;
    if (node >= N) return;
    int begin = __builtin_amdgcn_readfirstlane(start[node]);
    int end = __builtin_amdgcn_readfirstlane(endp[node]);
    const float4 er4 = *(const float4*)(er + (size_t)node * 4);

    float m0 = -INFINITY, m1 = -INFINITY, m2 = -INFINITY, m3 = -INFINITY;
    for (int e = begin + lane; e < end; e += 64) {
        int s = col[e];
        float4 e4 = *(const float4*)(el + (size_t)s * 4);
        m0 = fmaxf(m0, leaky(e4.x + er4.x));
        m1 = fmaxf(m1, leaky(e4.y + er4.y));
        m2 = fmaxf(m2, leaky(e4.z + er4.z));
        m3 = fmaxf(m3, leaky(e4.w + er4.w));
    }
#pragma unroll
    for (int off = 32; off >= 1; off >>= 1) {
        m0 = fmaxf(m0, __shfl_xor(m0, off));
        m1 = fmaxf(m1, __shfl_xor(m1, off));
        m2 = fmaxf(m2, __shfl_xor(m2, off));
        m3 = fmaxf(m3, __shfl_xor(m3, off));
    }
    float s0 = 0.f, s1 = 0.f, s2 = 0.f, s3 = 0.f;
    for (int e = begin + lane; e < end; e += 64) {
        int s = col[e];
        float4 e4 = *(const float4*)(el + (size_t)s * 4);
        s0 += __expf(leaky(e4.x + er4.x) - m0);
        s1 += __expf(leaky(e4.y + er4.y) - m1);
        s2 += __expf(leaky(e4.z + er4.z) - m2);
        s3 += __expf(leaky(e4.w + er4.w) - m3);
    }
#pragma unroll
    for (int off = 32; off >= 1; off >>= 1) {
        s0 += __shfl_xor(s0, off);
        s1 += __shfl_xor(s1, off);
        s2 += __shfl_xor(s2, off);
        s3 += __shfl_xor(s3, off);
    }

    int head = lane >> 4;
    float mh = (head & 2) ? ((head & 1) ? m3 : m2) : ((head & 1) ? m1 : m0);
    float sh = (head & 2) ? ((head & 1) ? s3 : s2) : ((head & 1) ? s1 : s0);
    float erh = (head & 2) ? ((head & 1) ? er4.w : er4.z) : ((head & 1) ? er4.y : er4.x);
    float inv = sh > 0.f ? 1.f / sh : 0.f;

    int ch = lane * 4;
    const unsigned short* fbase = feat + ch;
    float4 acc = {0.f, 0.f, 0.f, 0.f};
    int e = begin;
    for (; e + 1 < end; e += 2) {
        int sA = col[e], sB = col[e + 1];
        float wA = __expf(leaky(el[(size_t)sA * 4 + head] + erh) - mh) * inv;
        float wB = __expf(leaky(el[(size_t)sB * 4 + head] + erh) - mh) * inv;
        ushort4 uA = *(const ushort4*)(fbase + (size_t)sA * 256);
        ushort4 uB = *(const ushort4*)(fbase + (size_t)sB * 256);
        acc.x = fmaf(wA, bf2f(uA.x), acc.x); acc.y = fmaf(wA, bf2f(uA.y), acc.y);
        acc.z = fmaf(wA, bf2f(uA.z), acc.z); acc.w = fmaf(wA, bf2f(uA.w), acc.w);
        acc.x = fmaf(wB, bf2f(uB.x), acc.x); acc.y = fmaf(wB, bf2f(uB.y), acc.y);
        acc.z = fmaf(wB, bf2f(uB.z), acc.z); acc.w = fmaf(wB, bf2f(uB.w), acc.w);
    }
    if (e < end) {
        int sA = col[e];
        float wA = __expf(leaky(el[(size_t)sA * 4 + head] + erh) - mh) * inv;
        ushort4 uA = *(const ushort4*)(fbase + (size_t)sA * 256);
        acc.x = fmaf(wA, bf2f(uA.x), acc.x); acc.y = fmaf(wA, bf2f(uA.y), acc.y);
        acc.z = fmaf(wA, bf2f(uA.z), acc.z); acc.w = fmaf(wA, bf2f(uA.w), acc.w);
    }

    float4 bb = *(const float4*)(bias + ch);
    float x0 = acc.x + bb.x, x1 = acc.y + bb.y, x2 = acc.z + bb.z, x3 = acc.w + bb.w;
    x0 = x0 > 0.f ? x0 : expm1f(x0);
    x1 = x1 > 0.f ? x1 : expm1f(x1);
    x2 = x2 > 0.f ? x2 : expm1f(x2);
    x3 = x3 > 0.f ? x3 : expm1f(x3);
    float lsum = x0 + x1 + x2 + x3;
    float lsq = x0 * x0 + x1 * x1 + x2 * x2 + x3 * x3;
#pragma unroll
    for (int off = 32; off >= 1; off >>= 1) {
        lsum += __shfl_xor(lsum, off);
        lsq += __shfl_xor(lsq, off);
    }
    float mu = lsum * (1.f / 256.f);
    float var = lsq * (1.f / 256.f) - mu * mu;
    float rstd = rsqrtf(var + 1e-5f);
    float4 g4 = *(const float4*)(lng + ch);
    float4 b4 = *(const float4*)(lnb + ch);
    float4 hi = *(const float4*)(h_in + (size_t)node * 256 + ch);
    float y0 = (x0 - mu) * rstd * g4.x + b4.x;
    float y1 = (x1 - mu) * rstd * g4.y + b4.y;
    float y2 = (x2 - mu) * rstd * g4.z + b4.z;
    float y3 = (x3 - mu) * rstd * g4.w + b4.w;
    y0 = (y0 >= 0.f ? y0 : 0.2f * y0) + hi.x;
    y1 = (y1 >= 0.f ? y1 : 0.2f * y1) + hi.y;
    y2 = (y2 >= 0.f ? y2 : 0.2f * y2) + hi.z;
    y3 = (y3 >= 0.f ? y3 : 0.2f * y3) + hi.w;
    float4 out = {y0, y1, y2, y3};
    *(float4*)(h_out + (size_t)node * 256 + ch) = out;
}

// ---------------- output aggregation: logits[N,40] ----------------
__global__ __launch_bounds__(256) void aggregate_out(const unsigned short* __restrict__ feat_o,
                                                     const float* __restrict__ elo,
                                                     const float* __restrict__ ero,
                                                     const int* __restrict__ start,
                                                     const int* __restrict__ endp,
                                                     const int* __restrict__ col,
                                                     const float* __restrict__ bias_o,
                                                     float* __restrict__ out, int N) {
    int node = blockIdx.x * 4 + (threadIdx.x >> 6);
    int lane = threadIdx.x & 63;
    if (node >= N) return;
    int begin = __builtin_amdgcn_readfirstlane(start[node]);
    int end = __builtin_amdgcn_readfirstlane(endp[node]);
    float ern = ero[node];
    float m = -INFINITY;
    for (int e = begin + lane; e < end; e += 64) m = fmaxf(m, leaky(elo[col[e]] + ern));
#pragma unroll
    for (int off = 32; off >= 1; off >>= 1) m = fmaxf(m, __shfl_xor(m, off));
    float s = 0.f;
    for (int e = begin + lane; e < end; e += 64) s += __expf(leaky(elo[col[e]] + ern) - m);
#pragma unroll
    for (int off = 32; off >= 1; off >>= 1) s += __shfl_xor(s, off);
    float inv = s > 0.f ? 1.f / s : 0.f;
    int cc = lane < 40 ? lane : 0;
    float acc = 0.f;
    int e = begin;
    for (; e + 1 < end; e += 2) {
        int sA = col[e], sB = col[e + 1];
        float wA = __expf(leaky(elo[sA] + ern) - m) * inv;
        float wB = __expf(leaky(elo[sB] + ern) - m) * inv;
        float fA = bf2f(feat_o[(size_t)sA * 40 + cc]);
        float fB = bf2f(feat_o[(size_t)sB * 40 + cc]);
        acc = fmaf(wA, fA, acc);
        acc = fmaf(wB, fB, acc);
    }
    if (e < end) {
        int sA = col[e];
        float wA = __expf(leaky(elo[sA] + ern) - m) * inv;
        acc = fmaf(wA, bf2f(feat_o[(size_t)sA * 40 + cc]), acc);
    }
    if (lane < 40) out[(size_t)node * 40 + lane] = acc + bias_o[lane];
}

// ---------------- launcher ----------------
extern "C" void kernel_launch(void* const* d_in, const int* in_sizes, int n_in,
                              void* d_out, int out_size, void* d_ws, size_t ws_size,
                              hipStream_t stream) {
    const float* x = (const float*)d_in[0];
    const float* W_h = (const float*)d_in[1];
    const float* al_h = (const float*)d_in[2];
    const float* ar_h = (const float*)d_in[3];
    const float* bias_h = (const float*)d_in[4];
    const float* ln_g = (const float*)d_in[5];
    const float* ln_b = (const float*)d_in[6];
    const float* W_o = (const float*)d_in[7];
    const float* al_o = (const float*)d_in[8];
    const float* ar_o = (const float*)d_in[9];
    const float* bias_o = (const float*)d_in[10];
    const int* esrc = (const int*)d_in[11];
    const int* edst = (const int*)d_in[12];
    const int N = in_sizes[0] / 256;
    const int E = in_sizes[11];
    float* out = (float*)d_out;

    char* ws = (char*)d_ws;
    size_t off = 0;
    auto walloc = [&](size_t bytes) -> void* {
        void* p = ws + off;
        off += (bytes + 255) & ~(size_t)255;
        return p;
    };
    float* h = (float*)walloc((size_t)N * 256 * 4);
    unsigned short* feat_bf = (unsigned short*)walloc((size_t)N * 256 * 2);
    unsigned short* Wt = (unsigned short*)walloc((size_t)3 * 65536 * 2);
    unsigned short* Wt_o = (unsigned short*)walloc((size_t)48 * 256 * 2);
    float* el = (float*)walloc((size_t)N * 4 * 4);
    float* er = (float*)walloc((size_t)N * 4 * 4);
    int* counts = (int*)walloc(((size_t)N + 1) * 4);
    int* start = (int*)walloc((size_t)N * 4);
    int* endp = (int*)walloc((size_t)N * 4);
    int* col = (int*)walloc((size_t)E * 4);
    if (off > ws_size) return;

    const int TB = 256;
    transpose_w<<<3 * 65536 / TB, TB, 0, stream>>>(W_h, Wt);
    transpose_wo<<<48, TB, 0, stream>>>(W_o, Wt_o);
    zero_i32<<<(N + 1 + TB - 1) / TB, TB, 0, stream>>>(counts, N + 1);
    hist_kernel<<<(E + TB - 1) / TB, TB, 0, stream>>>(edst, counts, E);
    alloc_kernel<<<(N + TB - 1) / TB, TB, 0, stream>>>(counts, start, endp, counts + N, N);
    scatter_kernel<<<(E + TB - 1) / TB, TB, 0, stream>>>(esrc, edst, endp, col, E);

    const int nb4 = (N + 3) / 4;
    const int gemm_grid = ((N + 127) / 128) * 2;
    for (int l = 0; l < 3; ++l) {
        const float* hin = (l == 0) ? x : h;
        gemm_bf16<<<gemm_grid, 256, 0, stream>>>(hin, Wt + (size_t)l * 65536, feat_bf, N);
        scores_bf<<<nb4, 256, 0, stream>>>(feat_bf, al_h + l * 256, ar_h + l * 256, el, er, N);
        aggregate_hidden<<<nb4, 256, 0, stream>>>(feat_bf, el, er, start, endp, col,
                                                  bias_h + l * 256, ln_g + l * 256,
                                                  ln_b + l * 256, hin, h, N);
    }
    unsigned short* feat_o = feat_bf;
    float* elo = el;
    float* ero = er;
    gemm_out_mfma<<<(N + 127) / 128, 256, 0, stream>>>(h, Wt_o, feat_o, N);
    scores_out<<<nb4, 256, 0, stream>>>(feat_o, al_o, ar_o, elo, ero, N);
    aggregate_out<<<nb4, 256, 0, stream>>>(feat_o, elo, ero, start, endp, col, bias_o, out, N);
}